// Round 1
// baseline (258.657 us; speedup 1.0000x reference)
//
#include <hip/hip_runtime.h>

#define NG 12
#define SD 64
#define ED 768
#define NB 262144

// Precompute M[g][o] = sum_s Wg[g][s] * Wagg[o][g*64+s]
//            c0[o]  = bagg[o] + sum_{g,s} bg[g][s] * Wagg[o][g*64+s]
__global__ void fge_precompute(const float* __restrict__ Wg,
                               const float* __restrict__ bg,
                               const float* __restrict__ Wagg,
                               const float* __restrict__ bagg,
                               float* __restrict__ M,    // [12][768]
                               float* __restrict__ c0)   // [768]
{
    int o = blockIdx.x * blockDim.x + threadIdx.x;
    if (o >= ED) return;
    const float* wrow = Wagg + (size_t)o * ED;
    float csum = bagg[o];
    #pragma unroll 1
    for (int g = 0; g < NG; ++g) {
        float m = 0.f, cb = 0.f;
        #pragma unroll
        for (int s = 0; s < SD; ++s) {
            float w = wrow[g * SD + s];
            m  += Wg[g * SD + s] * w;
            cb += bg[g * SD + s] * w;
        }
        M[g * ED + o] = m;
        csum += cb;
    }
    c0[o] = csum;
}

// out[b][o] = c0[o] + sum_g counts[b][g] * M[g][o]
// Block = 192 threads; thread t owns output columns [t*4, t*4+4).
// M columns + c0 held in registers across the whole row loop.
__global__ __launch_bounds__(192) void fge_main(const int* __restrict__ counts,
                                                const float* __restrict__ M,
                                                const float* __restrict__ c0,
                                                float* __restrict__ out)
{
    const int t  = threadIdx.x;   // 0..191
    const int o0 = t * 4;

    float m[NG][4];
    #pragma unroll
    for (int g = 0; g < NG; ++g) {
        float4 v = *reinterpret_cast<const float4*>(M + g * ED + o0);
        m[g][0] = v.x; m[g][1] = v.y; m[g][2] = v.z; m[g][3] = v.w;
    }
    const float4 base = *reinterpret_cast<const float4*>(c0 + o0);

    for (int b = blockIdx.x; b < NB; b += gridDim.x) {
        // 12 ints, 48 B, 16B-aligned, wave-uniform address -> scalar loads
        const int4* cp = reinterpret_cast<const int4*>(counts + (size_t)b * NG);
        int4 ca = cp[0], cb = cp[1], cc = cp[2];
        float cf[NG] = { (float)ca.x, (float)ca.y, (float)ca.z, (float)ca.w,
                         (float)cb.x, (float)cb.y, (float)cb.z, (float)cb.w,
                         (float)cc.x, (float)cc.y, (float)cc.z, (float)cc.w };
        float4 acc = base;
        #pragma unroll
        for (int g = 0; g < NG; ++g) {
            acc.x = fmaf(cf[g], m[g][0], acc.x);
            acc.y = fmaf(cf[g], m[g][1], acc.y);
            acc.z = fmaf(cf[g], m[g][2], acc.z);
            acc.w = fmaf(cf[g], m[g][3], acc.w);
        }
        *reinterpret_cast<float4*>(out + (size_t)b * ED + o0) = acc;
    }
}

extern "C" void kernel_launch(void* const* d_in, const int* in_sizes, int n_in,
                              void* d_out, int out_size, void* d_ws, size_t ws_size,
                              hipStream_t stream) {
    const int*   counts = (const int*)  d_in[0];
    const float* Wg     = (const float*)d_in[1];
    const float* bg     = (const float*)d_in[2];
    const float* Wagg   = (const float*)d_in[3];
    const float* bagg   = (const float*)d_in[4];
    float* out = (float*)d_out;

    float* M  = (float*)d_ws;          // 12*768 floats = 36 KB
    float* c0 = M + NG * ED;           // 768 floats

    fge_precompute<<<(ED + 255) / 256, 256, 0, stream>>>(Wg, bg, Wagg, bagg, M, c0);
    fge_main<<<2048, 192, 0, stream>>>(counts, M, c0, out);
}